// Round 1
// 641.760 us; speedup vs baseline: 1.3232x; 1.3232x over previous
//
#include <hip/hip_runtime.h>

#define N_    32
#define CIN_  64
#define COUT_ 64
#define T_    1024
#define V_    25
#define K_    3
#define TT_   4        // t-values per gcn_main block
#define EPSV  1e-5f

// ws float offsets
#define WS_BIAS2  2112     // [64 c][25 w]
#define WS_SUM    9856     // [8 slot][64 c]
#define WS_SQ     10368
#define WS_SCALE  10880
#define WS_SHIFT  10944
#define WS_A2F    11008    // A2 B-frags: 5 nt * 64 lane * 8 bf16 = 2560 bf16 (1280 f)
#define WS_W2F    12288    // W2 B-frags: 24 g * 64 lane * 8 bf16 = 12288 bf16 (6144 f)

typedef __attribute__((ext_vector_type(4))) float f32x4;
typedef __attribute__((ext_vector_type(8))) short short8;   // 8 bf16 = 4 VGPRs

__device__ __forceinline__ unsigned short f_to_bf16u(float f) {
    unsigned int b = __float_as_uint(f);
    b += 0x7fffu + ((b >> 16) & 1u);   // RNE
    return (unsigned short)(b >> 16);
}

// ---- kernel 0: bias2, stat-zero, MFMA B-operand fragment tables ------------
// grid = 4 blocks x 256
__global__ void gcn_prep(const float* __restrict__ A, const float* __restrict__ PA,
                         const float* __restrict__ b, const float* __restrict__ W,
                         float* ws) {
    __shared__ float cs[K_ * V_];
    const int tid = threadIdx.x;
    const int blk = blockIdx.x;

    if (blk == 0) {
        if (tid < K_ * V_) {
            int k = tid / V_, w = tid % V_;
            float s = 0.f;
            for (int v = 0; v < V_; ++v) {
                int idx = (k * V_ + v) * V_ + w;
                s += A[idx] + PA[idx];
            }
            cs[tid] = s;
        }
        for (int f = tid; f < 1024; f += 256) ws[WS_SUM + f] = 0.f;
        __syncthreads();
        // bias2[c][w] = sum_k b[k*64+c] * colsum[k][w]
        for (int f = tid; f < COUT_ * V_; f += 256) {
            int c = f / V_, w = f - (f / V_) * V_;
            float s = 0.f;
            for (int k = 0; k < K_; ++k) s += b[k * COUT_ + c] * cs[k * V_ + w];
            ws[WS_BIAS2 + f] = s;
        }
    } else if (blk == 1) {
        // A2 frags (GEMM1 B-operand): col=(k,w)=nt*16+(l&15), kdim v=(l>>4)*8+j
        unsigned short* a2 = (unsigned short*)(ws + WS_A2F);
        for (int f = tid; f < 5 * 64 * 8; f += 256) {
            int j  = f & 7;
            int l  = (f >> 3) & 63;
            int nt = f >> 9;
            int col = nt * 16 + (l & 15);
            int v   = (l >> 4) * 8 + j;
            float val = 0.f;
            if (col < 75 && v < V_) {
                int k = col / 25, w = col - (col / 25) * 25;
                int idx = (k * V_ + v) * V_ + w;
                val = A[idx] + PA[idx];
            }
            a2[f] = f_to_bf16u(val);
        }
    } else {
        // W2 frags (GEMM2 B-operand): g = wv*6+kk; col c=(g/6)*16+(l&15),
        // kdim kci=(g%6)*32+(l>>4)*8+j ; value = W[(k*64+c)][ci]
        unsigned short* w2 = (unsigned short*)(ws + WS_W2F);
        int lo = (blk - 2) * 6144;
        for (int f = lo + tid; f < lo + 6144; f += 256) {
            int j = f & 7;
            int l = (f >> 3) & 63;
            int g = f >> 9;
            int kci = (g % 6) * 32 + (l >> 4) * 8 + j;
            int c   = (g / 6) * 16 + (l & 15);
            int k = kci >> 6, ci = kci & 63;
            w2[f] = f_to_bf16u(W[(k * 64 + c) * 64 + ci]);
        }
    }
}

// ---- kernel 1: fused conv+agg via two MFMA stages ---------------------------
// block = 256 (4 waves); grid = 32 n x 256 t-chunks = 8192
// LDS: X [256 rows=(ci*4+t)][40 v-pad] bf16 = 20480 B
//      xA [112 rows=(t*25+w)][200 (k,ci)-pad] bf16 = 44800 B   (total 65280)
//      epilogue aliases: ostage f32[64][101] @0, sstat f32[512] @25856
__global__ __launch_bounds__(256, 2)
void gcn_main(const float* __restrict__ x, float* __restrict__ ws,
              float* __restrict__ out) {
    __shared__ __align__(16) unsigned char smem[65280];
    unsigned short* xs16 = (unsigned short*)smem;
    unsigned short* xa16 = (unsigned short*)(smem + 20480);
    float* ostage = (float*)smem;
    float* sstat  = (float*)(smem + 25856);

    const int tid = threadIdx.x;
    const int bid = blockIdx.x;
    const int n   = bid >> 8;
    const int tc  = bid & 255;
    const int l   = tid & 63;
    const int wv  = tid >> 6;
    const int llo = l & 15;
    const int lhi = l >> 4;

    // zero X region (v-pad 25..39 must be 0 for the K=32 MFMA)
    {
        unsigned int* xu = (unsigned int*)xs16;
        #pragma unroll
        for (int i = 0; i < 20; ++i) xu[i * 256 + tid] = 0u;
    }
    __syncthreads();

    // ---- stage x -> bf16 LDS, coalesced float4 global reads ----
    const float4* xg = (const float4*)x;
    for (int f = tid; f < CIN_ * 25; f += 256) {
        int ci = f / 25;
        int j  = f - ci * 25;
        float4 g = xg[((size_t)(n * CIN_ + ci)) * 6400 + tc * 25 + j];
        int flat = 4 * j;
        int t = flat / 25;
        int v = flat - t * 25;
        float vals[4] = {g.x, g.y, g.z, g.w};
        #pragma unroll
        for (int e = 0; e < 4; ++e) {
            xs16[(ci * 4 + t) * 40 + v] = f_to_bf16u(vals[e]);
            if (++v == 25) { v = 0; ++t; }
        }
    }
    __syncthreads();

    // ---- GEMM1: xA[(t,w)][(k,ci)] = X[(ci,t)][v] x Af[v][(k,w)] ----
    {
        const unsigned short* a2g = (const unsigned short*)(ws + WS_A2F);
        short8 a2f[5];
        #pragma unroll
        for (int nt = 0; nt < 5; ++nt)
            a2f[nt] = *(const short8*)(a2g + (nt * 64 + l) * 8);

        #pragma unroll
        for (int q = 0; q < 4; ++q) {
            int mt = wv * 4 + q;
            short8 xf = *(const short8*)(xs16 + (mt * 16 + llo) * 40 + lhi * 8);
            f32x4 acc[5];
            #pragma unroll
            for (int nt = 0; nt < 5; ++nt) {
                f32x4 z = {0.f, 0.f, 0.f, 0.f};
                acc[nt] = __builtin_amdgcn_mfma_f32_16x16x32_bf16(xf, a2f[nt], z, 0, 0, 0);
            }
            // C1 lane mapping: col=(k,w)=nt*16+llo, rows=(ci,t): ci=mt*4+lhi, t=i
            int ci = mt * 4 + lhi;
            #pragma unroll
            for (int nt = 0; nt < 5; ++nt) {
                int col = nt * 16 + llo;
                if (col < 75) {
                    int k = (col >= 50) ? 2 : ((col >= 25) ? 1 : 0);
                    int w = col - k * 25;
                    unsigned short* dst = xa16 + w * 200 + k * 64 + ci;
                    #pragma unroll
                    for (int i = 0; i < 4; ++i)       // row2 = i*25+w
                        dst[i * 5000] = f_to_bf16u(acc[nt][i]);
                }
            }
        }
    }
    __syncthreads();

    // ---- GEMM2: out[(t,w)][c] = xA[(t,w)][(k,ci)] x W2[(k,ci)][c] + bias2 ----
    f32x4 c2[7];
    {
        const unsigned short* w2g = (const unsigned short*)(ws + WS_W2F);
        short8 w2f[6];
        #pragma unroll
        for (int kk = 0; kk < 6; ++kk)
            w2f[kk] = *(const short8*)(w2g + ((wv * 6 + kk) * 64 + l) * 8);

        const int c = wv * 16 + llo;
        #pragma unroll
        for (int mt = 0; mt < 7; ++mt) {
            f32x4 acc = {0.f, 0.f, 0.f, 0.f};
            #pragma unroll
            for (int kk = 0; kk < 6; ++kk) {
                short8 a = *(const short8*)(xa16 + (mt * 16 + llo) * 200 + kk * 32 + lhi * 8);
                acc = __builtin_amdgcn_mfma_f32_16x16x32_bf16(a, w2f[kk], acc, 0, 0, 0);
            }
            int rb = mt * 16 + lhi * 4;
            #pragma unroll
            for (int i = 0; i < 4; ++i) {
                int row2 = rb + i;
                if (row2 < 100) {
                    int t2 = row2 / 25;
                    int w2i = row2 - t2 * 25;
                    acc[i] += ws[WS_BIAS2 + c * 25 + w2i];
                }
            }
            c2[mt] = acc;
        }
    }
    __syncthreads();   // all xs/xa reads complete before ostage overwrite

    // ---- stage C2 to ostage[c][101] (conflict-free stride) ----
    {
        const int c = wv * 16 + llo;
        #pragma unroll
        for (int mt = 0; mt < 7; ++mt) {
            int rb = mt * 16 + lhi * 4;
            #pragma unroll
            for (int i = 0; i < 4; ++i)
                if (rb + i < 100) ostage[c * 101 + rb + i] = c2[mt][i];
        }
    }
    __syncthreads();

    // ---- coalesced global write: 6400 floats = 64 c x (4t*25w) ----
    const size_t obase = ((size_t)(n * COUT_)) * 25600 + tc * 100;
    #pragma unroll 1
    for (int it = 0; it < 25; ++it) {
        int idx = it * 256 + tid;
        int cc = idx / 100;
        int r  = idx - cc * 100;
        out[obase + (size_t)cc * 25600 + r] = ostage[cc * 101 + r];
    }

    // ---- per-(c,tg) stats from ostage + slotted atomics ----
    {
        int cc = tid & 63, tg = tid >> 6;
        float ls = 0.f, lq = 0.f;
        #pragma unroll
        for (int w = 0; w < 25; ++w) {
            float v = ostage[cc * 101 + tg * 25 + w];
            ls += v; lq = fmaf(v, v, lq);
        }
        sstat[(tg * 64 + cc) * 2]     = ls;
        sstat[(tg * 64 + cc) * 2 + 1] = lq;
    }
    __syncthreads();
    if (tid < 64) {
        int cc = tid;
        float s = sstat[cc * 2] + sstat[(64 + cc) * 2] + sstat[(128 + cc) * 2] + sstat[(192 + cc) * 2];
        float q = sstat[cc * 2 + 1] + sstat[(64 + cc) * 2 + 1] + sstat[(128 + cc) * 2 + 1] + sstat[(192 + cc) * 2 + 1];
        int slot = bid & 7;
        atomicAdd(&ws[WS_SUM + slot * 64 + cc], s);
        atomicAdd(&ws[WS_SQ  + slot * 64 + cc], q);
    }
}

// ---- kernel 2: finalize BN stats -------------------------------------------
__global__ void gcn_stats(float* ws, const float* __restrict__ gamma,
                          const float* __restrict__ beta) {
    int c = threadIdx.x;
    if (c < COUT_) {
        float s = 0.f, q = 0.f;
        #pragma unroll
        for (int slot = 0; slot < 8; ++slot) {
            s += ws[WS_SUM + slot * 64 + c];
            q += ws[WS_SQ  + slot * 64 + c];
        }
        const float cnt = (float)(N_ * T_ * V_);   // 819200
        float mu  = s / cnt;
        float var = q / cnt - mu * mu;
        float rs  = rsqrtf(var + EPSV);
        float sc  = gamma[c] * rs;
        ws[WS_SCALE + c] = sc;
        ws[WS_SHIFT + c] = fmaf(-mu, sc, beta[c]);
    }
}

// ---- kernel 3: BN apply + residual + ReLU, in-place on d_out ---------------
__global__ __launch_bounds__(256)
void gcn_finish(const float* __restrict__ x, const float* __restrict__ ws,
                float* __restrict__ out) {
    int bid = blockIdx.x;            // n*64 + c
    int c = bid & 63;
    float sc = ws[WS_SCALE + c];
    float sh = ws[WS_SHIFT + c];
    size_t base4 = (size_t)bid * 6400;
    const float4* x4 = (const float4*)x;
    float4* o4 = (float4*)out;
    #pragma unroll 2
    for (int it = 0; it < 25; ++it) {
        size_t i = base4 + it * 256 + threadIdx.x;
        float4 a  = o4[i];
        float4 xv = x4[i];
        a.x = fmaxf(0.f, fmaf(a.x, sc, sh) + xv.x);
        a.y = fmaxf(0.f, fmaf(a.y, sc, sh) + xv.y);
        a.z = fmaxf(0.f, fmaf(a.z, sc, sh) + xv.z);
        a.w = fmaxf(0.f, fmaf(a.w, sc, sh) + xv.w);
        o4[i] = a;
    }
}

extern "C" void kernel_launch(void* const* d_in, const int* in_sizes, int n_in,
                              void* d_out, int out_size, void* d_ws, size_t ws_size,
                              hipStream_t stream) {
    (void)in_sizes; (void)n_in; (void)out_size; (void)ws_size;
    const float* x     = (const float*)d_in[0];
    const float* W     = (const float*)d_in[1];
    const float* b     = (const float*)d_in[2];
    const float* A     = (const float*)d_in[3];
    const float* PA    = (const float*)d_in[4];
    const float* gamma = (const float*)d_in[5];
    const float* beta  = (const float*)d_in[6];
    float* out = (float*)d_out;
    float* ws  = (float*)d_ws;

    gcn_prep<<<4, 256, 0, stream>>>(A, PA, b, W, ws);
    gcn_main<<<N_ * (T_ / TT_), 256, 0, stream>>>(x, ws, out);
    gcn_stats<<<1, 64, 0, stream>>>(ws, gamma, beta);
    gcn_finish<<<N_ * COUT_, 256, 0, stream>>>(x, ws, out);
}